// Round 2
// baseline (777.154 us; speedup 1.0000x reference)
//
#include <hip/hip_runtime.h>
#include <hip/hip_bf16.h>
#include <math.h>

typedef unsigned short u16;
typedef __attribute__((ext_vector_type(8))) short bf16x8;
typedef __attribute__((ext_vector_type(4))) float f32x4;
typedef __attribute__((ext_vector_type(4))) unsigned int uint4v;

#define BB 2
#define LL 2048
#define KN 48
#define HH 128
#define NBLK (BB*LL)
#define SA 392   /* LDS stride for 48x384 A tile (196 dwords % 32 == 4) */
#define SM 136   /* LDS stride for 48x128 m tiles (68 dwords % 32 == 4) */

/* workspace layout in u16 units from (u16*)d_ws:
   [0..15]: flags (2 ints in first 8 bytes)           */
#define WOFF      16
#define OFF_W1T   (WOFF + 0)        /* [128][384] */
#define OFF_W2T   (WOFF + 49152)    /* [128][128] */
#define OFF_W3T   (WOFF + 65536)
#define OFF_W11T  (WOFF + 81920)
#define OFF_W12T  (WOFF + 131072)
#define OFF_W13T  (WOFF + 147456)
#define OFF_WIT   (WOFF + 163840)   /* [512][128] */
#define OFF_WOT   (WOFF + 229376)   /* [128][512] */
#define OFF_HVN   (WOFF + 294912)   /* [B*L][128] new h_V, bf16 */
#define PREP_N    294912

__device__ __forceinline__ float b2f(u16 u){
    union { unsigned int i; float f; } v; v.i = ((unsigned int)u) << 16; return v.f;
}
__device__ __forceinline__ u16 f2b(float f){
    unsigned int x = __float_as_uint(f);
    unsigned int r = x + 0x7fffu + ((x >> 16) & 1u);
    return (u16)(r >> 16);
}
__device__ __forceinline__ float gelu_f(float x){
    return 0.5f * x * (1.0f + erff(x * 0.70710678118654752f));
}
/* adaptive loads: f32 flag selects fp32 vs bf16 interpretation */
__device__ __forceinline__ u16 ldb(const void* p, long i, int f32){
    return f32 ? f2b(((const float*)p)[i]) : ((const u16*)p)[i];
}
__device__ __forceinline__ float ldf(const void* p, long i, int f32){
    return f32 ? ((const float*)p)[i] : b2f(((const u16*)p)[i]);
}
__device__ __forceinline__ void stage8(u16* dst, const void* src, long off, int f32){
    if (f32){
        const float* s = (const float*)src + off;
#pragma unroll
        for (int j = 0; j < 8; j++) dst[j] = f2b(s[j]);
    } else {
        *(uint4v*)dst = *(const uint4v*)((const u16*)src + off);
    }
}
__device__ __forceinline__ int ld_idx(const void* p, int i, int i64){
    int v = i64 ? ((const int*)p)[2*i] : ((const int*)p)[i];
    return v & (LL - 1);   /* clamp: never OOB even if decode is wrong */
}
__device__ __forceinline__ void st_out(void* p, long i, float v, int f32){
    if (f32) ((float*)p)[i] = v;
    else ((u16*)p)[i] = f2b(v);
}
__device__ __forceinline__ float dot8(const float* x, bf16x8 wv){
    return x[0]*b2f((u16)wv[0]) + x[1]*b2f((u16)wv[1]) + x[2]*b2f((u16)wv[2]) + x[3]*b2f((u16)wv[3])
         + x[4]*b2f((u16)wv[4]) + x[5]*b2f((u16)wv[5]) + x[6]*b2f((u16)wv[6]) + x[7]*b2f((u16)wv[7]);
}

/* ---- dtype detection ---- */
__global__ void detect_kernel(const void* ln1s, const void* maskV, const void* eidx, int* flags){
    if (threadIdx.x == 0){
        unsigned l0 = ((const unsigned*)ln1s)[0];   /* ones: fp32=0x3F800000, bf16=0x3F803F80 */
        unsigned m0 = ((const unsigned*)maskV)[0];
        int f32 = (l0 == 0x3F800000u || m0 == 0x3F800000u) ? 1 : 0;
        const int* e = (const int*)eidx;
        int orodd = 0, orlow = 0;
        for (int i = 1; i < 64; i += 2) orodd |= e[i];
        for (int i = 0; i < 64; i += 2) orlow |= e[i];
        flags[0] = f32;
        flags[1] = (orodd == 0 && orlow != 0) ? 1 : 0;  /* int64 */
    }
}

/* ---- weight transpose prep (adaptive source dtype, bf16 dest) ---- */
__global__ void prep_kernel(const void* W1, const void* W2, const void* W3,
                            const void* W11, const void* W12, const void* W13,
                            const void* Wi, const void* Wo, u16* wsbase){
    const int f32 = ((const int*)wsbase)[0];
    int i = blockIdx.x * 256 + threadIdx.x;
    if (i < 49152){ int n = i / 384, k = i % 384; wsbase[OFF_W1T + i] = ldb(W1, k*128 + n, f32); }
    else if (i < 65536){ int j = i - 49152;  int n = j >> 7, k = j & 127; wsbase[OFF_W2T  + j] = ldb(W2, k*128 + n, f32); }
    else if (i < 81920){ int j = i - 65536;  int n = j >> 7, k = j & 127; wsbase[OFF_W3T  + j] = ldb(W3, k*128 + n, f32); }
    else if (i < 131072){ int j = i - 81920; int n = j / 384, k = j % 384; wsbase[OFF_W11T + j] = ldb(W11, k*128 + n, f32); }
    else if (i < 147456){ int j = i - 131072; int n = j >> 7, k = j & 127; wsbase[OFF_W12T + j] = ldb(W12, k*128 + n, f32); }
    else if (i < 163840){ int j = i - 147456; int n = j >> 7, k = j & 127; wsbase[OFF_W13T + j] = ldb(W13, k*128 + n, f32); }
    else if (i < 229376){ int j = i - 163840; int h = j >> 7, c = j & 127; wsbase[OFF_WIT + j] = ldb(Wi, c*512 + h, f32); }
    else if (i < 294912){ int j = i - 229376; int c = j >> 9, h = j & 511; wsbase[OFF_WOT + j] = ldb(Wo, h*128 + c, f32); }
}

/* ---- GEMM piece: C[48x128], 4 waves x (3 m-tiles x 2 n-tiles) ---- */
template<int KD, int STRIDE>
__device__ __forceinline__ void mfma_gemm(const u16* Als, const u16* WT,
                                          f32x4 acc[3][2], int lane, int w){
    const int r16 = lane & 15;
    const int q8  = (lane >> 4) * 8;
    const u16* ap = Als + r16 * STRIDE + q8;
    const u16* bp = WT + (w * 32 + r16) * KD + q8;
#pragma unroll
    for (int kk = 0; kk < KD; kk += 32){
        bf16x8 a0 = *(const bf16x8*)(ap + kk);
        bf16x8 a1 = *(const bf16x8*)(ap + 16 * STRIDE + kk);
        bf16x8 a2 = *(const bf16x8*)(ap + 32 * STRIDE + kk);
        bf16x8 b0 = *(const bf16x8*)(bp + kk);
        bf16x8 b1 = *(const bf16x8*)(bp + 16 * KD + kk);
        acc[0][0] = __builtin_amdgcn_mfma_f32_16x16x32_bf16(a0, b0, acc[0][0], 0, 0, 0);
        acc[1][0] = __builtin_amdgcn_mfma_f32_16x16x32_bf16(a1, b0, acc[1][0], 0, 0, 0);
        acc[2][0] = __builtin_amdgcn_mfma_f32_16x16x32_bf16(a2, b0, acc[2][0], 0, 0, 0);
        acc[0][1] = __builtin_amdgcn_mfma_f32_16x16x32_bf16(a0, b1, acc[0][1], 0, 0, 0);
        acc[1][1] = __builtin_amdgcn_mfma_f32_16x16x32_bf16(a1, b1, acc[1][1], 0, 0, 0);
        acc[2][1] = __builtin_amdgcn_mfma_f32_16x16x32_bf16(a2, b1, acc[2][1], 0, 0, 0);
    }
}

__device__ __forceinline__ void zero_acc(f32x4 acc[3][2]){
#pragma unroll
    for (int m = 0; m < 3; m++)
#pragma unroll
        for (int n = 0; n < 2; n++){ acc[m][n][0]=0.f; acc[m][n][1]=0.f; acc[m][n][2]=0.f; acc[m][n][3]=0.f; }
}

__device__ __forceinline__ void store_m(f32x4 acc[3][2], u16* M, const void* bias, int f32,
                                        int lane, int w, bool dogelu){
    const int r16 = lane & 15, q = lane >> 4;
#pragma unroll
    for (int nt = 0; nt < 2; nt++){
        int col = w * 32 + nt * 16 + r16;
        float bc = ldf(bias, col, f32);
#pragma unroll
        for (int mt = 0; mt < 3; mt++)
#pragma unroll
            for (int i = 0; i < 4; i++){
                int r = mt * 16 + q * 4 + i;
                float v = acc[mt][nt][i] + bc;
                if (dogelu) v = gelu_f(v);
                M[r * SM + col] = f2b(v);
            }
    }
}

/* ---- kernel 1: node message + LN1 + FFN + LN2 ---- */
__global__ __launch_bounds__(256, 2) void node_kernel(
    const void* __restrict__ hV, const void* __restrict__ hE, const void* __restrict__ Eidx,
    const void* __restrict__ maskV, const void* __restrict__ maskA,
    const void* __restrict__ b1, const void* __restrict__ b2, const void* __restrict__ b3,
    const void* __restrict__ bi, const void* __restrict__ bo,
    const void* __restrict__ ln1s, const void* __restrict__ ln1b,
    const void* __restrict__ ln2s, const void* __restrict__ ln2b,
    u16* __restrict__ wsbase, void* __restrict__ dout)
{
    __shared__ alignas(16) u16 A[KN * SA];
    __shared__ alignas(16) u16 M1[KN * SM];
    __shared__ alignas(16) u16 M2[KN * SM];
    __shared__ float smask[KN];
    __shared__ float dh[HH];
    __shared__ float xbuf[HH];
    __shared__ float hid[512];

    const int f32 = ((const int*)wsbase)[0];
    const int i64 = ((const int*)wsbase)[1];
    const u16* ws = wsbase;
    const int t = threadIdx.x, lane = t & 63, w = t >> 6;
    const int bid = blockIdx.x;
    const int b = bid >> 11;

    for (int i = t; i < 768; i += 256){
        int row = i >> 4, ch = i & 15;
        stage8(A + row * SA + 128 + ch * 8, hE, ((long)bid * KN + row) * HH + ch * 8, f32);
    }
    for (int i = t; i < 768; i += 256){
        int row = i >> 4, ch = i & 15;
        stage8(A + row * SA + ch * 8, hV, (long)bid * HH + ch * 8, f32);
    }
    for (int i = t; i < 768; i += 256){
        int row = i >> 4, ch = i & 15;
        int nb = ld_idx(Eidx, bid * KN + row, i64);
        stage8(A + row * SA + 256 + ch * 8, hV, ((long)b * LL + nb) * HH + ch * 8, f32);
    }
    if (t < KN) smask[t] = ldf(maskA, bid * KN + t, f32);
    __syncthreads();

    f32x4 acc[3][2];
    zero_acc(acc);
    mfma_gemm<384, SA>(A, ws + OFF_W1T, acc, lane, w);
    store_m(acc, M1, b1, f32, lane, w, true);
    __syncthreads();

    zero_acc(acc);
    mfma_gemm<128, SM>(M1, ws + OFF_W2T, acc, lane, w);
    store_m(acc, M2, b2, f32, lane, w, true);
    __syncthreads();

    zero_acc(acc);
    mfma_gemm<128, SM>(M2, ws + OFF_W3T, acc, lane, w);

    /* masked k-reduction -> dh */
    {
        const int r16 = lane & 15, q = lane >> 4;
        float bc0 = ldf(b3, w * 32 + r16, f32);
        float bc1 = ldf(b3, w * 32 + 16 + r16, f32);
        float s0 = 0.f, s1 = 0.f;
#pragma unroll
        for (int mt = 0; mt < 3; mt++)
#pragma unroll
            for (int i = 0; i < 4; i++){
                int r = mt * 16 + q * 4 + i;
                float mk = smask[r];
                s0 += mk * (acc[mt][0][i] + bc0);
                s1 += mk * (acc[mt][1][i] + bc1);
            }
        s0 += __shfl_xor(s0, 16); s0 += __shfl_xor(s0, 32);
        s1 += __shfl_xor(s1, 16); s1 += __shfl_xor(s1, 32);
        if (lane < 16){ dh[w * 32 + lane] = s0; dh[w * 32 + 16 + lane] = s1; }
    }
    __syncthreads();

    /* LN1 (wave 0) */
    if (w == 0){
        float xa = b2f(A[lane])      + dh[lane]      * (1.0f / 30.0f);
        float xb = b2f(A[64 + lane]) + dh[64 + lane] * (1.0f / 30.0f);
        float sum = xa + xb, sq = xa * xa + xb * xb;
#pragma unroll
        for (int off = 1; off < 64; off <<= 1){ sum += __shfl_xor(sum, off); sq += __shfl_xor(sq, off); }
        float mu = sum * (1.0f / 128.0f);
        float var = sq * (1.0f / 128.0f) - mu * mu;
        float rstd = rsqrtf(var + 1e-5f);
        xbuf[lane]      = (xa - mu) * rstd * ldf(ln1s, lane, f32)      + ldf(ln1b, lane, f32);
        xbuf[64 + lane] = (xb - mu) * rstd * ldf(ln1s, 64 + lane, f32) + ldf(ln1b, 64 + lane, f32);
    }
    __syncthreads();

    /* FFN hidden */
    for (int h = t; h < 512; h += 256){
        const u16* wrow = ws + OFF_WIT + h * 128;
        float sum = ldf(bi, h, f32);
#pragma unroll
        for (int c = 0; c < 128; c += 8)
            sum += dot8(xbuf + c, *(const bf16x8*)(wrow + c));
        hid[h] = gelu_f(sum);
    }
    __syncthreads();

    /* FFN out */
    {
        int c = t >> 1, half = t & 1;
        const u16* wrow = ws + OFF_WOT + c * 512 + half * 256;
        const float* hp = hid + half * 256;
        float sum = 0.f;
#pragma unroll
        for (int h2 = 0; h2 < 256; h2 += 8)
            sum += dot8(hp + h2, *(const bf16x8*)(wrow + h2));
        float other = __shfl_xor(sum, 1);
        if (half == 0) dh[c] = sum + other + ldf(bo, c, f32);
    }
    __syncthreads();

    /* LN2 + mask_V + store */
    if (w == 0){
        float xa = xbuf[lane]      + dh[lane];
        float xb = xbuf[64 + lane] + dh[64 + lane];
        float sum = xa + xb, sq = xa * xa + xb * xb;
#pragma unroll
        for (int off = 1; off < 64; off <<= 1){ sum += __shfl_xor(sum, off); sq += __shfl_xor(sq, off); }
        float mu = sum * (1.0f / 128.0f);
        float var = sq * (1.0f / 128.0f) - mu * mu;
        float rstd = rsqrtf(var + 1e-5f);
        float mv = ldf(maskV, bid, f32);
        float y0 = ((xa - mu) * rstd * ldf(ln2s, lane, f32)      + ldf(ln2b, lane, f32)) * mv;
        float y1 = ((xb - mu) * rstd * ldf(ln2s, 64 + lane, f32) + ldf(ln2b, 64 + lane, f32)) * mv;
        wsbase[OFF_HVN + (long)bid * HH + lane]      = f2b(y0);
        wsbase[OFF_HVN + (long)bid * HH + 64 + lane] = f2b(y1);
        st_out(dout, (long)bid * HH + lane, y0, f32);
        st_out(dout, (long)bid * HH + 64 + lane, y1, f32);
    }
}

/* ---- kernel 2: edge update + LN3 ---- */
__global__ __launch_bounds__(256, 2) void edge_kernel(
    const void* __restrict__ hE, const void* __restrict__ Eidx,
    const void* __restrict__ b11, const void* __restrict__ b12, const void* __restrict__ b13,
    const void* __restrict__ ln3s, const void* __restrict__ ln3b,
    u16* __restrict__ wsbase, void* __restrict__ dout)
{
    __shared__ alignas(16) u16 A[KN * SA];
    __shared__ alignas(16) u16 M1[KN * SM];
    __shared__ alignas(16) u16 M2[KN * SM];
    __shared__ float rowsum[KN];
    __shared__ float rowsq[KN];

    const int f32 = ((const int*)wsbase)[0];
    const int i64 = ((const int*)wsbase)[1];
    const u16* ws = wsbase;
    const u16* hv2 = wsbase + OFF_HVN;   /* new h_V, bf16 */
    const int t = threadIdx.x, lane = t & 63, w = t >> 6;
    const int bid = blockIdx.x;
    const int b = bid >> 11;

    for (int i = t; i < 768; i += 256){
        int row = i >> 4, ch = i & 15;
        stage8(A + row * SA + 128 + ch * 8, hE, ((long)bid * KN + row) * HH + ch * 8, f32);
    }
    for (int i = t; i < 768; i += 256){
        int row = i >> 4, ch = i & 15;
        stage8(A + row * SA + ch * 8, hv2, (long)bid * HH + ch * 8, 0);
    }
    for (int i = t; i < 768; i += 256){
        int row = i >> 4, ch = i & 15;
        int nb = ld_idx(Eidx, bid * KN + row, i64);
        stage8(A + row * SA + 256 + ch * 8, hv2, ((long)b * LL + nb) * HH + ch * 8, 0);
    }
    if (t < KN){ rowsum[t] = 0.f; rowsq[t] = 0.f; }
    __syncthreads();

    f32x4 acc[3][2];
    zero_acc(acc);
    mfma_gemm<384, SA>(A, ws + OFF_W11T, acc, lane, w);
    store_m(acc, M1, b11, f32, lane, w, true);
    __syncthreads();

    zero_acc(acc);
    mfma_gemm<128, SM>(M1, ws + OFF_W12T, acc, lane, w);
    store_m(acc, M2, b12, f32, lane, w, true);
    __syncthreads();

    zero_acc(acc);
    mfma_gemm<128, SM>(M2, ws + OFF_W13T, acc, lane, w);

    const int r16 = lane & 15, q = lane >> 4;
    float vals[3][2][4];
    {
        float bc0 = ldf(b13, w * 32 + r16, f32);
        float bc1 = ldf(b13, w * 32 + 16 + r16, f32);
#pragma unroll
        for (int mt = 0; mt < 3; mt++)
#pragma unroll
            for (int i = 0; i < 4; i++){
                int r = mt * 16 + q * 4 + i;
                float v0 = acc[mt][0][i] + bc0 + b2f(A[r * SA + 128 + w * 32 + r16]);
                float v1 = acc[mt][1][i] + bc1 + b2f(A[r * SA + 128 + w * 32 + 16 + r16]);
                vals[mt][0][i] = v0; vals[mt][1][i] = v1;
                atomicAdd(&rowsum[r], v0 + v1);
                atomicAdd(&rowsq[r], v0 * v0 + v1 * v1);
            }
    }
    __syncthreads();
    if (t < KN){
        float mu = rowsum[t] * (1.0f / 128.0f);
        float var = rowsq[t] * (1.0f / 128.0f) - mu * mu;
        rowsum[t] = mu;
        rowsq[t] = rsqrtf(var + 1e-5f);
    }
    __syncthreads();

    {
        long ebase = (long)BB * LL * HH;   /* element offset of h_E in d_out */
        float g0 = ldf(ln3s, w * 32 + r16, f32),      be0 = ldf(ln3b, w * 32 + r16, f32);
        float g1 = ldf(ln3s, w * 32 + 16 + r16, f32), be1 = ldf(ln3b, w * 32 + 16 + r16, f32);
#pragma unroll
        for (int mt = 0; mt < 3; mt++)
#pragma unroll
            for (int i = 0; i < 4; i++){
                int r = mt * 16 + q * 4 + i;
                float mu = rowsum[r], rstd = rowsq[r];
                long base = ebase + ((long)bid * KN + r) * HH;
                st_out(dout, base + w * 32 + r16,      (vals[mt][0][i] - mu) * rstd * g0 + be0, f32);
                st_out(dout, base + w * 32 + 16 + r16, (vals[mt][1][i] - mu) * rstd * g1 + be1, f32);
            }
    }
}

extern "C" void kernel_launch(void* const* d_in, const int* in_sizes, int n_in,
                              void* d_out, int out_size, void* d_ws, size_t ws_size,
                              hipStream_t stream) {
    const void* hV    = d_in[0];
    const void* hE    = d_in[1];
    const void* Eidx  = d_in[2];
    const void* maskV = d_in[3];
    const void* maskA = d_in[4];
    const void* W1  = d_in[5];  const void* b1  = d_in[6];
    const void* W2  = d_in[7];  const void* b2  = d_in[8];
    const void* W3  = d_in[9];  const void* b3  = d_in[10];
    const void* W11 = d_in[11]; const void* b11 = d_in[12];
    const void* W12 = d_in[13]; const void* b12 = d_in[14];
    const void* W13 = d_in[15]; const void* b13 = d_in[16];
    const void* Wi  = d_in[17]; const void* bi  = d_in[18];
    const void* Wo  = d_in[19]; const void* bo  = d_in[20];
    const void* ln1s = d_in[21]; const void* ln1b = d_in[22];
    const void* ln2s = d_in[23]; const void* ln2b = d_in[24];
    const void* ln3s = d_in[25]; const void* ln3b = d_in[26];

    u16* ws = (u16*)d_ws;

    detect_kernel<<<1, 64, 0, stream>>>(ln1s, maskV, Eidx, (int*)d_ws);
    prep_kernel<<<(PREP_N + 255) / 256, 256, 0, stream>>>(W1, W2, W3, W11, W12, W13, Wi, Wo, ws);
    node_kernel<<<NBLK, 256, 0, stream>>>(hV, hE, Eidx, maskV, maskA,
                                          b1, b2, b3, bi, bo,
                                          ln1s, ln1b, ln2s, ln2b, ws, d_out);
    edge_kernel<<<NBLK, 256, 0, stream>>>(hE, Eidx, b11, b12, b13,
                                          ln3s, ln3b, ws, d_out);
}

// Round 3
// 626.081 us; speedup vs baseline: 1.2413x; 1.2413x over previous
//
#include <hip/hip_runtime.h>
#include <hip/hip_bf16.h>
#include <math.h>

typedef unsigned short u16;
typedef __attribute__((ext_vector_type(8))) short bf16x8;
typedef __attribute__((ext_vector_type(4))) float f32x4;
typedef __attribute__((ext_vector_type(4))) unsigned int uint4v;

#define BB 2
#define LL 2048
#define KN 48
#define HH 128
#define NBLK (BB*LL)
#define SA 264   /* LDS stride for 48x256 A tile (132 dwords % 32 == 4) */
#define SM 136   /* LDS stride for 48x128 m tiles (68 dwords % 32 == 4) */

/* workspace layout in u16 units from (u16*)d_ws: [0..15]: flags */
#define WOFF      16
#define OFF_W1T   (WOFF + 0)        /* [128][384] */
#define OFF_W2T   (WOFF + 49152)    /* [128][128] */
#define OFF_W3T   (WOFF + 65536)
#define OFF_W11T  (WOFF + 81920)
#define OFF_W12T  (WOFF + 131072)
#define OFF_W13T  (WOFF + 147456)
#define OFF_WIT   (WOFF + 163840)   /* [512][128] */
#define OFF_WOT   (WOFF + 229376)   /* [128][512] */
#define OFF_HVN   (WOFF + 294912)   /* [B*L][128] new h_V, bf16 */
#define PREP_N    294912

__device__ __forceinline__ float b2f(u16 u){
    union { unsigned int i; float f; } v; v.i = ((unsigned int)u) << 16; return v.f;
}
__device__ __forceinline__ u16 f2b(float f){
    unsigned int x = __float_as_uint(f);
    unsigned int r = x + 0x7fffu + ((x >> 16) & 1u);
    return (u16)(r >> 16);
}
__device__ __forceinline__ float gelu_f(float x){
    return 0.5f * x * (1.0f + erff(x * 0.70710678118654752f));
}
__device__ __forceinline__ u16 ldb(const void* p, long i, int f32){
    return f32 ? f2b(((const float*)p)[i]) : ((const u16*)p)[i];
}
__device__ __forceinline__ float ldf(const void* p, long i, int f32){
    return f32 ? ((const float*)p)[i] : b2f(((const u16*)p)[i]);
}
__device__ __forceinline__ void stage8(u16* dst, const void* src, long off, int f32){
    if (f32){
        const float* s = (const float*)src + off;
#pragma unroll
        for (int j = 0; j < 8; j++) dst[j] = f2b(s[j]);
    } else {
        *(uint4v*)dst = *(const uint4v*)((const u16*)src + off);
    }
}
__device__ __forceinline__ int ld_idx(const void* p, int i, int i64){
    int v = i64 ? ((const int*)p)[2*i] : ((const int*)p)[i];
    return v & (LL - 1);
}
__device__ __forceinline__ void st_out(void* p, long i, float v, int f32){
    if (f32) ((float*)p)[i] = v;
    else ((u16*)p)[i] = f2b(v);
}

/* ---- dtype detection ---- */
__global__ void detect_kernel(const void* ln1s, const void* maskV, const void* eidx, int* flags){
    if (threadIdx.x == 0){
        unsigned l0 = ((const unsigned*)ln1s)[0];
        unsigned m0 = ((const unsigned*)maskV)[0];
        int f32 = (l0 == 0x3F800000u || m0 == 0x3F800000u) ? 1 : 0;
        const int* e = (const int*)eidx;
        int orodd = 0, orlow = 0;
        for (int i = 1; i < 64; i += 2) orodd |= e[i];
        for (int i = 0; i < 64; i += 2) orlow |= e[i];
        flags[0] = f32;
        flags[1] = (orodd == 0 && orlow != 0) ? 1 : 0;
    }
}

/* ---- weight transpose prep ---- */
__global__ void prep_kernel(const void* W1, const void* W2, const void* W3,
                            const void* W11, const void* W12, const void* W13,
                            const void* Wi, const void* Wo, u16* wsbase){
    const int f32 = ((const int*)wsbase)[0];
    int i = blockIdx.x * 256 + threadIdx.x;
    if (i < 49152){ int n = i / 384, k = i % 384; wsbase[OFF_W1T + i] = ldb(W1, k*128 + n, f32); }
    else if (i < 65536){ int j = i - 49152;  int n = j >> 7, k = j & 127; wsbase[OFF_W2T  + j] = ldb(W2, k*128 + n, f32); }
    else if (i < 81920){ int j = i - 65536;  int n = j >> 7, k = j & 127; wsbase[OFF_W3T  + j] = ldb(W3, k*128 + n, f32); }
    else if (i < 131072){ int j = i - 81920; int n = j / 384, k = j % 384; wsbase[OFF_W11T + j] = ldb(W11, k*128 + n, f32); }
    else if (i < 147456){ int j = i - 131072; int n = j >> 7, k = j & 127; wsbase[OFF_W12T + j] = ldb(W12, k*128 + n, f32); }
    else if (i < 163840){ int j = i - 147456; int n = j >> 7, k = j & 127; wsbase[OFF_W13T + j] = ldb(W13, k*128 + n, f32); }
    else if (i < 229376){ int j = i - 163840; int h = j >> 7, c = j & 127; wsbase[OFF_WIT + j] = ldb(Wi, c*512 + h, f32); }
    else if (i < 294912){ int j = i - 229376; int c = j >> 9, h = j & 511; wsbase[OFF_WOT + j] = ldb(Wo, h*128 + c, f32); }
}

/* ---- GEMM piece: 48 rows x 16 cols per wave (wave w = n-tile w) ----
   WTbase must point at row 0 of the weight's K-contiguous layout;
   WROW = row length, KOFF = starting k offset into each row. */
template<int KSTEPS, int STRIDE, int WROW, int KOFF>
__device__ __forceinline__ void mfma_gemm8(const u16* Als, const u16* WTbase,
                                           f32x4 acc[3], int lane, int w){
    const int r16 = lane & 15;
    const int q8  = (lane >> 4) * 8;
    const u16* ap = Als + r16 * STRIDE + q8;
    const u16* bp = WTbase + (w * 16 + r16) * WROW + KOFF + q8;
#pragma unroll
    for (int kk = 0; kk < KSTEPS * 32; kk += 32){
        bf16x8 b0 = *(const bf16x8*)(bp + kk);
        bf16x8 a0 = *(const bf16x8*)(ap + kk);
        bf16x8 a1 = *(const bf16x8*)(ap + 16 * STRIDE + kk);
        bf16x8 a2 = *(const bf16x8*)(ap + 32 * STRIDE + kk);
        acc[0] = __builtin_amdgcn_mfma_f32_16x16x32_bf16(a0, b0, acc[0], 0, 0, 0);
        acc[1] = __builtin_amdgcn_mfma_f32_16x16x32_bf16(a1, b0, acc[1], 0, 0, 0);
        acc[2] = __builtin_amdgcn_mfma_f32_16x16x32_bf16(a2, b0, acc[2], 0, 0, 0);
    }
}

__device__ __forceinline__ void zero_acc3(f32x4 acc[3]){
#pragma unroll
    for (int m = 0; m < 3; m++){ acc[m][0]=0.f; acc[m][1]=0.f; acc[m][2]=0.f; acc[m][3]=0.f; }
}

__device__ __forceinline__ void store_m8(f32x4 acc[3], u16* M, float bc,
                                         int lane, int w, bool dogelu){
    const int r16 = lane & 15, q = lane >> 4;
    int col = w * 16 + r16;
#pragma unroll
    for (int mt = 0; mt < 3; mt++)
#pragma unroll
        for (int i = 0; i < 4; i++){
            int r = mt * 16 + q * 4 + i;
            float v = acc[mt][i] + bc;
            if (dogelu) v = gelu_f(v);
            M[r * SM + col] = f2b(v);
        }
}

/* per-wave effective bias: beff[n] = bias[n] + sum_k hv0[k]*WT[n][k], n in wave's 16 cols */
__device__ __forceinline__ void calc_beff(const float* hv0, const u16* WT, const void* bias,
                                          float* beff, int f32, int lane, int w){
    int n = w * 16 + (lane >> 2);
    int p = lane & 3;
    const u16* wr = WT + (long)n * 384 + p * 32;
    float s = 0.f;
#pragma unroll
    for (int k = 0; k < 32; k++) s += hv0[p * 32 + k] * b2f(wr[k]);
    s += __shfl_xor(s, 1);
    s += __shfl_xor(s, 2);
    if (p == 0) beff[n] = ldf(bias, n, f32) + s;
}

/* ---- kernel 1: node message + LN1 + FFN + LN2 ---- */
__global__ __launch_bounds__(512, 6) void node_kernel(
    const void* __restrict__ hV, const void* __restrict__ hE, const void* __restrict__ Eidx,
    const void* __restrict__ maskV, const void* __restrict__ maskA,
    const void* __restrict__ b1, const void* __restrict__ b2, const void* __restrict__ b3,
    const void* __restrict__ bi, const void* __restrict__ bo,
    const void* __restrict__ ln1s, const void* __restrict__ ln1b,
    const void* __restrict__ ln2s, const void* __restrict__ ln2b,
    u16* __restrict__ wsbase, void* __restrict__ dout)
{
    __shared__ alignas(16) u16 A[KN * SA];     /* [h_E | gather], M2 aliases this */
    __shared__ alignas(16) u16 M1[KN * SM];
    __shared__ float smask[KN];
    __shared__ float dh[HH];
    __shared__ float xbuf[HH];
    __shared__ float hid[512];
    __shared__ float hv0[HH];
    __shared__ float beff[HH];
    u16* M2 = A;

    const int f32 = ((const int*)wsbase)[0];
    const int i64 = ((const int*)wsbase)[1];
    const u16* ws = wsbase;
    const int t = threadIdx.x, lane = t & 63, w = t >> 6;
    const int bid = blockIdx.x;
    const int b = bid >> 11;

    for (int i = t; i < 768; i += 512){
        int row = i >> 4, ch = i & 15;
        stage8(A + row * SA + ch * 8, hE, ((long)bid * KN + row) * HH + ch * 8, f32);
    }
    for (int i = t; i < 768; i += 512){
        int row = i >> 4, ch = i & 15;
        int nb = ld_idx(Eidx, bid * KN + row, i64);
        stage8(A + row * SA + 128 + ch * 8, hV, ((long)b * LL + nb) * HH + ch * 8, f32);
    }
    if (t < HH) hv0[t] = ldf(hV, (long)bid * HH + t, f32);
    if (t < KN) smask[t] = ldf(maskA, bid * KN + t, f32);
    __syncthreads();

    calc_beff(hv0, ws + OFF_W1T, b1, beff, f32, lane, w);

    f32x4 acc[3];
    zero_acc3(acc);
    mfma_gemm8<8, SA, 384, 128>(A, ws + OFF_W1T, acc, lane, w);
    store_m8(acc, M1, beff[w * 16 + (lane & 15)], lane, w, true);
    __syncthreads();

    zero_acc3(acc);
    mfma_gemm8<4, SM, 128, 0>(M1, ws + OFF_W2T, acc, lane, w);
    store_m8(acc, M2, ldf(b2, w * 16 + (lane & 15), f32), lane, w, true);
    __syncthreads();

    zero_acc3(acc);
    mfma_gemm8<4, SM, 128, 0>(M2, ws + OFF_W3T, acc, lane, w);

    /* masked k-reduction -> dh */
    {
        const int r16 = lane & 15, q = lane >> 4;
        float bc = ldf(b3, w * 16 + r16, f32);
        float s0 = 0.f;
#pragma unroll
        for (int mt = 0; mt < 3; mt++)
#pragma unroll
            for (int i = 0; i < 4; i++){
                int r = mt * 16 + q * 4 + i;
                s0 += smask[r] * (acc[mt][i] + bc);
            }
        s0 += __shfl_xor(s0, 16); s0 += __shfl_xor(s0, 32);
        if (lane < 16) dh[w * 16 + lane] = s0;
    }
    __syncthreads();

    /* LN1 (wave 0) */
    if (w == 0){
        float xa = hv0[lane]      + dh[lane]      * (1.0f / 30.0f);
        float xb = hv0[64 + lane] + dh[64 + lane] * (1.0f / 30.0f);
        float sum = xa + xb, sq = xa * xa + xb * xb;
#pragma unroll
        for (int off = 1; off < 64; off <<= 1){ sum += __shfl_xor(sum, off); sq += __shfl_xor(sq, off); }
        float mu = sum * (1.0f / 128.0f);
        float var = sq * (1.0f / 128.0f) - mu * mu;
        float rstd = rsqrtf(var + 1e-5f);
        xbuf[lane]      = (xa - mu) * rstd * ldf(ln1s, lane, f32)      + ldf(ln1b, lane, f32);
        xbuf[64 + lane] = (xb - mu) * rstd * ldf(ln1s, 64 + lane, f32) + ldf(ln1b, 64 + lane, f32);
    }
    __syncthreads();

    /* FFN hidden: one unit per thread */
    {
        const u16* wrow = ws + OFF_WIT + t * 128;
        float sum = ldf(bi, t, f32);
#pragma unroll
        for (int c = 0; c < 128; c += 8){
            bf16x8 wv = *(const bf16x8*)(wrow + c);
#pragma unroll
            for (int j = 0; j < 8; j++) sum += xbuf[c + j] * b2f((u16)wv[j]);
        }
        hid[t] = gelu_f(sum);
    }
    __syncthreads();

    /* FFN out: 4 threads per col */
    {
        int c = t >> 2, p = t & 3;
        const u16* wrow = ws + OFF_WOT + c * 512 + p * 128;
        const float* hp = hid + p * 128;
        float sum = 0.f;
#pragma unroll
        for (int h2 = 0; h2 < 128; h2 += 8){
            bf16x8 wv = *(const bf16x8*)(wrow + h2);
#pragma unroll
            for (int j = 0; j < 8; j++) sum += hp[h2 + j] * b2f((u16)wv[j]);
        }
        sum += __shfl_xor(sum, 1);
        sum += __shfl_xor(sum, 2);
        if (p == 0) dh[c] = sum + ldf(bo, c, f32);
    }
    __syncthreads();

    /* LN2 + mask_V + store */
    if (w == 0){
        float xa = xbuf[lane]      + dh[lane];
        float xb = xbuf[64 + lane] + dh[64 + lane];
        float sum = xa + xb, sq = xa * xa + xb * xb;
#pragma unroll
        for (int off = 1; off < 64; off <<= 1){ sum += __shfl_xor(sum, off); sq += __shfl_xor(sq, off); }
        float mu = sum * (1.0f / 128.0f);
        float var = sq * (1.0f / 128.0f) - mu * mu;
        float rstd = rsqrtf(var + 1e-5f);
        float mv = ldf(maskV, bid, f32);
        float y0 = ((xa - mu) * rstd * ldf(ln2s, lane, f32)      + ldf(ln2b, lane, f32)) * mv;
        float y1 = ((xb - mu) * rstd * ldf(ln2s, 64 + lane, f32) + ldf(ln2b, 64 + lane, f32)) * mv;
        wsbase[OFF_HVN + (long)bid * HH + lane]      = f2b(y0);
        wsbase[OFF_HVN + (long)bid * HH + 64 + lane] = f2b(y1);
        st_out(dout, (long)bid * HH + lane, y0, f32);
        st_out(dout, (long)bid * HH + 64 + lane, y1, f32);
    }
}

/* ---- kernel 2: edge update + LN3 ---- */
__global__ __launch_bounds__(512, 6) void edge_kernel(
    const void* __restrict__ hE, const void* __restrict__ Eidx,
    const void* __restrict__ b11, const void* __restrict__ b12, const void* __restrict__ b13,
    const void* __restrict__ ln3s, const void* __restrict__ ln3b,
    u16* __restrict__ wsbase, void* __restrict__ dout)
{
    __shared__ alignas(16) u16 A[KN * SA];     /* [h_E | gather], h_E kept for residual */
    __shared__ alignas(16) u16 M1[KN * SM];
    __shared__ alignas(16) u16 M2[KN * SM];
    __shared__ float rowsum[KN];
    __shared__ float rowsq[KN];
    __shared__ float hv0[HH];
    __shared__ float beff[HH];

    const int f32 = ((const int*)wsbase)[0];
    const int i64 = ((const int*)wsbase)[1];
    const u16* ws = wsbase;
    const u16* hv2 = wsbase + OFF_HVN;
    const int t = threadIdx.x, lane = t & 63, w = t >> 6;
    const int bid = blockIdx.x;
    const int b = bid >> 11;

    for (int i = t; i < 768; i += 512){
        int row = i >> 4, ch = i & 15;
        stage8(A + row * SA + ch * 8, hE, ((long)bid * KN + row) * HH + ch * 8, f32);
    }
    for (int i = t; i < 768; i += 512){
        int row = i >> 4, ch = i & 15;
        int nb = ld_idx(Eidx, bid * KN + row, i64);
        stage8(A + row * SA + 128 + ch * 8, hv2, ((long)b * LL + nb) * HH + ch * 8, 0);
    }
    if (t < HH) hv0[t] = b2f(hv2[(long)bid * HH + t]);
    if (t < KN){ rowsum[t] = 0.f; rowsq[t] = 0.f; }
    __syncthreads();

    calc_beff(hv0, ws + OFF_W11T, b11, beff, f32, lane, w);

    f32x4 acc[3];
    zero_acc3(acc);
    mfma_gemm8<8, SA, 384, 128>(A, ws + OFF_W11T, acc, lane, w);
    store_m8(acc, M1, beff[w * 16 + (lane & 15)], lane, w, true);
    __syncthreads();

    zero_acc3(acc);
    mfma_gemm8<4, SM, 128, 0>(M1, ws + OFF_W12T, acc, lane, w);
    store_m8(acc, M2, ldf(b12, w * 16 + (lane & 15), f32), lane, w, true);
    __syncthreads();

    zero_acc3(acc);
    mfma_gemm8<4, SM, 128, 0>(M2, ws + OFF_W13T, acc, lane, w);

    const int r16 = lane & 15, q = lane >> 4;
    const int c0 = w * 16 + r16;
    float vals[3][4];
    {
        float bc = ldf(b13, c0, f32);
#pragma unroll
        for (int mt = 0; mt < 3; mt++)
#pragma unroll
            for (int i = 0; i < 4; i++){
                int r = mt * 16 + q * 4 + i;
                float v = acc[mt][i] + bc + b2f(A[r * SA + c0]);
                vals[mt][i] = v;
            }
    }
    /* row stats: reduce over the 16 col-lanes first, then one atomic per group */
#pragma unroll
    for (int mt = 0; mt < 3; mt++)
#pragma unroll
        for (int i = 0; i < 4; i++){
            float s = vals[mt][i], sq = vals[mt][i] * vals[mt][i];
            s += __shfl_xor(s, 1); sq += __shfl_xor(sq, 1);
            s += __shfl_xor(s, 2); sq += __shfl_xor(sq, 2);
            s += __shfl_xor(s, 4); sq += __shfl_xor(sq, 4);
            s += __shfl_xor(s, 8); sq += __shfl_xor(sq, 8);
            if (r16 == 0){
                int r = mt * 16 + q * 4 + i;
                atomicAdd(&rowsum[r], s);
                atomicAdd(&rowsq[r], sq);
            }
        }
    __syncthreads();
    if (t < KN){
        float mu = rowsum[t] * (1.0f / 128.0f);
        float var = rowsq[t] * (1.0f / 128.0f) - mu * mu;
        rowsum[t] = mu;
        rowsq[t] = rsqrtf(var + 1e-5f);
    }
    __syncthreads();

    {
        long ebase = (long)BB * LL * HH;
        float g = ldf(ln3s, c0, f32), be = ldf(ln3b, c0, f32);
#pragma unroll
        for (int mt = 0; mt < 3; mt++)
#pragma unroll
            for (int i = 0; i < 4; i++){
                int r = mt * 16 + q * 4 + i;
                long base = ebase + ((long)bid * KN + r) * HH;
                st_out(dout, base + c0, (vals[mt][i] - rowsum[r]) * rowsq[r] + be, f32);
            }
    }
}

extern "C" void kernel_launch(void* const* d_in, const int* in_sizes, int n_in,
                              void* d_out, int out_size, void* d_ws, size_t ws_size,
                              hipStream_t stream) {
    const void* hV    = d_in[0];
    const void* hE    = d_in[1];
    const void* Eidx  = d_in[2];
    const void* maskV = d_in[3];
    const void* maskA = d_in[4];
    const void* W1  = d_in[5];  const void* b1  = d_in[6];
    const void* W2  = d_in[7];  const void* b2  = d_in[8];
    const void* W3  = d_in[9];  const void* b3  = d_in[10];
    const void* W11 = d_in[11]; const void* b11 = d_in[12];
    const void* W12 = d_in[13]; const void* b12 = d_in[14];
    const void* W13 = d_in[15]; const void* b13 = d_in[16];
    const void* Wi  = d_in[17]; const void* bi  = d_in[18];
    const void* Wo  = d_in[19]; const void* bo  = d_in[20];
    const void* ln1s = d_in[21]; const void* ln1b = d_in[22];
    const void* ln2s = d_in[23]; const void* ln2b = d_in[24];
    const void* ln3s = d_in[25]; const void* ln3b = d_in[26];

    u16* ws = (u16*)d_ws;

    detect_kernel<<<1, 64, 0, stream>>>(ln1s, maskV, Eidx, (int*)d_ws);
    prep_kernel<<<(PREP_N + 255) / 256, 256, 0, stream>>>(W1, W2, W3, W11, W12, W13, Wi, Wo, ws);
    node_kernel<<<NBLK, 512, 0, stream>>>(hV, hE, Eidx, maskV, maskA,
                                          b1, b2, b3, bi, bo,
                                          ln1s, ln1b, ln2s, ln2b, ws, d_out);
    edge_kernel<<<NBLK, 512, 0, stream>>>(hE, Eidx, b11, b12, b13,
                                          ln3s, ln3b, ws, d_out);
}

// Round 4
// 439.634 us; speedup vs baseline: 1.7677x; 1.4241x over previous
//
#include <hip/hip_runtime.h>
#include <hip/hip_bf16.h>
#include <math.h>

typedef unsigned short u16;
typedef __attribute__((ext_vector_type(8))) short bf16x8;
typedef __attribute__((ext_vector_type(4))) float f32x4;
typedef __attribute__((ext_vector_type(4))) unsigned int uint4v;

#define BB 2
#define LL 2048
#define KN 48
#define HH 128
#define NBLK (BB*LL)
#define SA 264   /* LDS stride for 48x256 A tile (132 dwords % 32 == 4) */
#define SM 136   /* LDS stride for 48x128 m tiles (68 dwords % 32 == 4) */

/* workspace layout in u16 units from (u16*)d_ws: [0..15]: flags */
#define WOFF      16
#define OFF_W1T   (WOFF + 0)        /* [128][384] */
#define OFF_W2T   (WOFF + 49152)    /* [128][128] */
#define OFF_W3T   (WOFF + 65536)
#define OFF_W11T  (WOFF + 81920)
#define OFF_W12T  (WOFF + 131072)
#define OFF_W13T  (WOFF + 147456)
#define OFF_WIT   (WOFF + 163840)   /* [512][128] */
#define OFF_WOT   (WOFF + 229376)   /* [128][512] */
#define OFF_HV1   (WOFF + 294912)   /* [B*L][128] LN1 output, bf16 */
#define PREP_N    294912

__device__ __forceinline__ float b2f(u16 u){
    union { unsigned int i; float f; } v; v.i = ((unsigned int)u) << 16; return v.f;
}
__device__ __forceinline__ u16 f2b(float f){
    unsigned int x = __float_as_uint(f);
    unsigned int r = x + 0x7fffu + ((x >> 16) & 1u);
    return (u16)(r >> 16);
}
__device__ __forceinline__ float gelu_f(float x){
    return 0.5f * x * (1.0f + erff(x * 0.70710678118654752f));
}
__device__ __forceinline__ u16 ldb(const void* p, long i, int f32){
    return f32 ? f2b(((const float*)p)[i]) : ((const u16*)p)[i];
}
__device__ __forceinline__ float ldf(const void* p, long i, int f32){
    return f32 ? ((const float*)p)[i] : b2f(((const u16*)p)[i]);
}
__device__ __forceinline__ void stage8(u16* dst, const void* src, long off, int f32){
    if (f32){
        const float* s = (const float*)src + off;
#pragma unroll
        for (int j = 0; j < 8; j++) dst[j] = f2b(s[j]);
    } else {
        *(uint4v*)dst = *(const uint4v*)((const u16*)src + off);
    }
}
__device__ __forceinline__ int ld_idx(const void* p, int i, int i64){
    int v = i64 ? ((const int*)p)[2*i] : ((const int*)p)[i];
    return v & (LL - 1);
}
__device__ __forceinline__ void st_out(void* p, long i, float v, int f32){
    if (f32) ((float*)p)[i] = v;
    else ((u16*)p)[i] = f2b(v);
}

/* ---- dtype detection ---- */
__global__ void detect_kernel(const void* ln1s, const void* maskV, const void* eidx, int* flags){
    if (threadIdx.x == 0){
        unsigned l0 = ((const unsigned*)ln1s)[0];
        unsigned m0 = ((const unsigned*)maskV)[0];
        int f32 = (l0 == 0x3F800000u || m0 == 0x3F800000u) ? 1 : 0;
        const int* e = (const int*)eidx;
        int orodd = 0, orlow = 0;
        for (int i = 1; i < 64; i += 2) orodd |= e[i];
        for (int i = 0; i < 64; i += 2) orlow |= e[i];
        flags[0] = f32;
        flags[1] = (orodd == 0 && orlow != 0) ? 1 : 0;
    }
}

/* ---- weight transpose prep ---- */
__global__ void prep_kernel(const void* W1, const void* W2, const void* W3,
                            const void* W11, const void* W12, const void* W13,
                            const void* Wi, const void* Wo, u16* wsbase){
    const int f32 = ((const int*)wsbase)[0];
    int i = blockIdx.x * 256 + threadIdx.x;
    if (i < 49152){ int n = i / 384, k = i % 384; wsbase[OFF_W1T + i] = ldb(W1, k*128 + n, f32); }
    else if (i < 65536){ int j = i - 49152;  int n = j >> 7, k = j & 127; wsbase[OFF_W2T  + j] = ldb(W2, k*128 + n, f32); }
    else if (i < 81920){ int j = i - 65536;  int n = j >> 7, k = j & 127; wsbase[OFF_W3T  + j] = ldb(W3, k*128 + n, f32); }
    else if (i < 131072){ int j = i - 81920; int n = j / 384, k = j % 384; wsbase[OFF_W11T + j] = ldb(W11, k*128 + n, f32); }
    else if (i < 147456){ int j = i - 131072; int n = j >> 7, k = j & 127; wsbase[OFF_W12T + j] = ldb(W12, k*128 + n, f32); }
    else if (i < 163840){ int j = i - 147456; int n = j >> 7, k = j & 127; wsbase[OFF_W13T + j] = ldb(W13, k*128 + n, f32); }
    else if (i < 229376){ int j = i - 163840; int h = j >> 7, c = j & 127; wsbase[OFF_WIT + j] = ldb(Wi, c*512 + h, f32); }
    else if (i < 294912){ int j = i - 229376; int c = j >> 9, h = j & 511; wsbase[OFF_WOT + j] = ldb(Wo, h*128 + c, f32); }
}

/* ---- GEMM with register-resident B: 48 rows x 16 cols per wave ---- */
template<int KSTEPS, int STRIDE>
__device__ __forceinline__ void mfma_regB(const u16* Als, const bf16x8* B,
                                          f32x4 acc[3], int lane){
    const int r16 = lane & 15;
    const int q8  = (lane >> 4) * 8;
    const u16* ap = Als + r16 * STRIDE + q8;
#pragma unroll
    for (int kk = 0; kk < KSTEPS; kk++){
        bf16x8 a0 = *(const bf16x8*)(ap + kk * 32);
        bf16x8 a1 = *(const bf16x8*)(ap + 16 * STRIDE + kk * 32);
        bf16x8 a2 = *(const bf16x8*)(ap + 32 * STRIDE + kk * 32);
        acc[0] = __builtin_amdgcn_mfma_f32_16x16x32_bf16(a0, B[kk], acc[0], 0, 0, 0);
        acc[1] = __builtin_amdgcn_mfma_f32_16x16x32_bf16(a1, B[kk], acc[1], 0, 0, 0);
        acc[2] = __builtin_amdgcn_mfma_f32_16x16x32_bf16(a2, B[kk], acc[2], 0, 0, 0);
    }
}

__device__ __forceinline__ void zero_acc3(f32x4 acc[3]){
#pragma unroll
    for (int m = 0; m < 3; m++){ acc[m][0]=0.f; acc[m][1]=0.f; acc[m][2]=0.f; acc[m][3]=0.f; }
}

__device__ __forceinline__ void store_m8(f32x4 acc[3], u16* M, float bc,
                                         int lane, int w, bool dogelu){
    const int r16 = lane & 15, q = lane >> 4;
    int col = w * 16 + r16;
#pragma unroll
    for (int mt = 0; mt < 3; mt++)
#pragma unroll
        for (int i = 0; i < 4; i++){
            int r = mt * 16 + q * 4 + i;
            float v = acc[mt][i] + bc;
            if (dogelu) v = gelu_f(v);
            M[r * SM + col] = f2b(v);
        }
}

/* beff[n] = bias[n] + sum_k hv0[k]*WT[n][k] (the folded broadcast-h_V part) */
__device__ __forceinline__ void calc_beff(const float* hv0, const u16* WT, const void* bias,
                                          float* beff, int f32, int lane, int w){
    int n = w * 16 + (lane >> 2);
    int p = lane & 3;
    const u16* wr = WT + (long)n * 384 + p * 32;
    float s = 0.f;
#pragma unroll
    for (int k = 0; k < 32; k++) s += hv0[p * 32 + k] * b2f(wr[k]);
    s += __shfl_xor(s, 1);
    s += __shfl_xor(s, 2);
    if (p == 0) beff[n] = ldf(bias, n, f32) + s;
}

/* ---- kernel 1: node message + LN1 -> hv1 (ws) ---- */
__global__ __launch_bounds__(512, 6) void node_kernel(
    const void* __restrict__ hV, const void* __restrict__ hE, const void* __restrict__ Eidx,
    const void* __restrict__ maskA,
    const void* __restrict__ b1, const void* __restrict__ b2, const void* __restrict__ b3,
    const void* __restrict__ ln1s, const void* __restrict__ ln1b,
    u16* __restrict__ wsbase)
{
    __shared__ alignas(16) u16 A[KN * SA];   /* [h_E | gather]; M2 aliases */
    __shared__ alignas(16) u16 M1[KN * SM];
    __shared__ float smask[KN];
    __shared__ float dh[HH];
    __shared__ float hv0f[HH];
    __shared__ float beff[HH];
    u16* M2 = A;

    const int f32 = ((const int*)wsbase)[0];
    const int i64 = ((const int*)wsbase)[1];
    const u16* ws = wsbase;
    const int t = threadIdx.x, lane = t & 63, w = t >> 6;
    const int bid = blockIdx.x;
    const int b = bid >> 11;
    const int r16 = lane & 15, q8 = (lane >> 4) * 8;

    /* prefetch B1 (GEMM1 weights, cols for this wave) into registers */
    bf16x8 B1[8];
    {
        const u16* bp = ws + OFF_W1T + (long)(w * 16 + r16) * 384 + 128 + q8;
#pragma unroll
        for (int k = 0; k < 8; k++) B1[k] = *(const bf16x8*)(bp + k * 32);
    }

    for (int i = t; i < 768; i += 512){
        int row = i >> 4, ch = i & 15;
        stage8(A + row * SA + ch * 8, hE, ((long)bid * KN + row) * HH + ch * 8, f32);
    }
    for (int i = t; i < 768; i += 512){
        int row = i >> 4, ch = i & 15;
        int nb = ld_idx(Eidx, bid * KN + row, i64);
        stage8(A + row * SA + 128 + ch * 8, hV, ((long)b * LL + nb) * HH + ch * 8, f32);
    }
    if (t < HH) hv0f[t] = ldf(hV, (long)bid * HH + t, f32);
    if (t < KN) smask[t] = ldf(maskA, bid * KN + t, f32);

    /* prefetch B2 */
    bf16x8 B2[4];
    {
        const u16* bp = ws + OFF_W2T + (long)(w * 16 + r16) * 128 + q8;
#pragma unroll
        for (int k = 0; k < 4; k++) B2[k] = *(const bf16x8*)(bp + k * 32);
    }
    __syncthreads();

    calc_beff(hv0f, ws + OFF_W1T, b1, beff, f32, lane, w);

    f32x4 acc[3];
    zero_acc3(acc);
    mfma_regB<8, SA>(A, B1, acc, lane);
    store_m8(acc, M1, beff[w * 16 + r16], lane, w, true);

    /* prefetch B3 while waiting */
    bf16x8 B3[4];
    {
        const u16* bp = ws + OFF_W3T + (long)(w * 16 + r16) * 128 + q8;
#pragma unroll
        for (int k = 0; k < 4; k++) B3[k] = *(const bf16x8*)(bp + k * 32);
    }
    __syncthreads();

    zero_acc3(acc);
    mfma_regB<4, SM>(M1, B2, acc, lane);
    store_m8(acc, M2, ldf(b2, w * 16 + r16, f32), lane, w, true);
    __syncthreads();

    zero_acc3(acc);
    mfma_regB<4, SM>(M2, B3, acc, lane);

    /* masked k-reduction -> dh */
    {
        const int q = lane >> 4;
        float bc = ldf(b3, w * 16 + r16, f32);
        float s0 = 0.f;
#pragma unroll
        for (int mt = 0; mt < 3; mt++)
#pragma unroll
            for (int i = 0; i < 4; i++){
                int r = mt * 16 + q * 4 + i;
                s0 += smask[r] * (acc[mt][i] + bc);
            }
        s0 += __shfl_xor(s0, 16); s0 += __shfl_xor(s0, 32);
        if (lane < 16) dh[w * 16 + lane] = s0;
    }
    __syncthreads();

    /* LN1 (wave 0) -> hv1 bf16 */
    if (w == 0){
        float xa = hv0f[lane]      + dh[lane]      * (1.0f / 30.0f);
        float xb = hv0f[64 + lane] + dh[64 + lane] * (1.0f / 30.0f);
        float sum = xa + xb, sq = xa * xa + xb * xb;
#pragma unroll
        for (int off = 1; off < 64; off <<= 1){ sum += __shfl_xor(sum, off); sq += __shfl_xor(sq, off); }
        float mu = sum * (1.0f / 128.0f);
        float var = sq * (1.0f / 128.0f) - mu * mu;
        float rstd = rsqrtf(var + 1e-5f);
        wsbase[OFF_HV1 + (long)bid * HH + lane] =
            f2b((xa - mu) * rstd * ldf(ln1s, lane, f32) + ldf(ln1b, lane, f32));
        wsbase[OFF_HV1 + (long)bid * HH + 64 + lane] =
            f2b((xb - mu) * rstd * ldf(ln1s, 64 + lane, f32) + ldf(ln1b, 64 + lane, f32));
    }
}

/* ---- kernel 2: FFN over 16 nodes/block (MFMA) + LN2 + mask -> d_out h_V ---- */
__global__ __launch_bounds__(512, 6) void ffn_kernel(
    const void* __restrict__ maskV,
    const void* __restrict__ bi, const void* __restrict__ bo,
    const void* __restrict__ ln2s, const void* __restrict__ ln2b,
    u16* __restrict__ wsbase, void* __restrict__ dout)
{
    __shared__ alignas(16) u16 X[16 * 136];
    __shared__ alignas(16) u16 Hid[16 * 520];
    __shared__ float V[16 * 132];

    const int f32 = ((const int*)wsbase)[0];
    const u16* ws = wsbase;
    const u16* hv1 = wsbase + OFF_HV1;
    const int t = threadIdx.x, lane = t & 63, w = t >> 6;
    const int node0 = blockIdx.x * 16;
    const int r16 = lane & 15, q = lane >> 4, q8 = q * 8;

    if (t < 256){
        int row = t >> 4, ch = t & 15;
        *(uint4v*)(X + row * 136 + ch * 8) =
            *(const uint4v*)(hv1 + (long)(node0 + row) * HH + ch * 8);
    }
    __syncthreads();

    /* GEMM1: [16x128] @ WiT -> wave w covers cols [w*64, w*64+64) */
    bf16x8 a[4];
    {
        const u16* ap = X + r16 * 136 + q8;
#pragma unroll
        for (int kk = 0; kk < 4; kk++) a[kk] = *(const bf16x8*)(ap + kk * 32);
    }
    f32x4 acc[4];
#pragma unroll
    for (int nt = 0; nt < 4; nt++){
        acc[nt][0]=0.f; acc[nt][1]=0.f; acc[nt][2]=0.f; acc[nt][3]=0.f;
        int n = w * 64 + nt * 16 + r16;
        const u16* bp = ws + OFF_WIT + (long)n * 128 + q8;
#pragma unroll
        for (int kk = 0; kk < 4; kk++){
            bf16x8 bv = *(const bf16x8*)(bp + kk * 32);
            acc[nt] = __builtin_amdgcn_mfma_f32_16x16x32_bf16(a[kk], bv, acc[nt], 0, 0, 0);
        }
    }
#pragma unroll
    for (int nt = 0; nt < 4; nt++){
        int col = w * 64 + nt * 16 + r16;
        float bc = ldf(bi, col, f32);
#pragma unroll
        for (int i = 0; i < 4; i++){
            int row = q * 4 + i;
            Hid[row * 520 + col] = f2b(gelu_f(acc[nt][i] + bc));
        }
    }
    __syncthreads();

    /* GEMM2: [16x512] @ WoT -> wave w covers cols w*16+r16; K=512 */
    f32x4 acc2; acc2[0]=0.f; acc2[1]=0.f; acc2[2]=0.f; acc2[3]=0.f;
    {
        const u16* ap = Hid + r16 * 520 + q8;
        const u16* bp = ws + OFF_WOT + (long)(w * 16 + r16) * 512 + q8;
#pragma unroll
        for (int kk = 0; kk < 16; kk++){
            bf16x8 av = *(const bf16x8*)(ap + kk * 32);
            bf16x8 bv = *(const bf16x8*)(bp + kk * 32);
            acc2 = __builtin_amdgcn_mfma_f32_16x16x32_bf16(av, bv, acc2, 0, 0, 0);
        }
    }
    {
        int col = w * 16 + r16;
        float bc = ldf(bo, col, f32);
#pragma unroll
        for (int i = 0; i < 4; i++){
            int row = q * 4 + i;
            V[row * 132 + col] = acc2[i] + bc + b2f(X[row * 136 + col]);
        }
    }
    __syncthreads();

    /* LN2 + mask: 32 threads per row, 4 cols each */
    {
        int row = t >> 5, p = t & 31;
        float v0 = V[row * 132 + p * 4 + 0];
        float v1 = V[row * 132 + p * 4 + 1];
        float v2 = V[row * 132 + p * 4 + 2];
        float v3 = V[row * 132 + p * 4 + 3];
        float sum = v0 + v1 + v2 + v3;
        float sq = v0*v0 + v1*v1 + v2*v2 + v3*v3;
#pragma unroll
        for (int off = 1; off < 32; off <<= 1){ sum += __shfl_xor(sum, off); sq += __shfl_xor(sq, off); }
        float mu = sum * (1.0f / 128.0f);
        float var = sq * (1.0f / 128.0f) - mu * mu;
        float rstd = rsqrtf(var + 1e-5f);
        float mv = ldf(maskV, node0 + row, f32);
        long base = (long)(node0 + row) * HH;
#pragma unroll
        for (int j = 0; j < 4; j++){
            int c = p * 4 + j;
            float v = (j==0)?v0:(j==1)?v1:(j==2)?v2:v3;
            float y = ((v - mu) * rstd * ldf(ln2s, c, f32) + ldf(ln2b, c, f32)) * mv;
            st_out(dout, base + c, y, f32);
        }
    }
}

/* ---- kernel 3: edge update + LN3 (gathers h_V from d_out) ---- */
__global__ __launch_bounds__(512, 6) void edge_kernel(
    const void* __restrict__ hE, const void* __restrict__ Eidx,
    const void* __restrict__ b11, const void* __restrict__ b12, const void* __restrict__ b13,
    const void* __restrict__ ln3s, const void* __restrict__ ln3b,
    u16* __restrict__ wsbase, void* __restrict__ dout)
{
    __shared__ alignas(16) u16 A[KN * SA];   /* [h_E | gather]; M2 aliases */
    __shared__ alignas(16) u16 M1[KN * SM];
    __shared__ float rowsum[KN];
    __shared__ float rowsq[KN];
    __shared__ float hv0f[HH];
    __shared__ float beff[HH];
    u16* M2 = A;

    const int f32 = ((const int*)wsbase)[0];
    const int i64 = ((const int*)wsbase)[1];
    const u16* ws = wsbase;
    const int t = threadIdx.x, lane = t & 63, w = t >> 6;
    const int bid = blockIdx.x;
    const int b = bid >> 11;
    const int r16 = lane & 15, q8 = (lane >> 4) * 8;

    bf16x8 B1[8];
    {
        const u16* bp = ws + OFF_W11T + (long)(w * 16 + r16) * 384 + 128 + q8;
#pragma unroll
        for (int k = 0; k < 8; k++) B1[k] = *(const bf16x8*)(bp + k * 32);
    }

    for (int i = t; i < 768; i += 512){
        int row = i >> 4, ch = i & 15;
        stage8(A + row * SA + ch * 8, hE, ((long)bid * KN + row) * HH + ch * 8, f32);
    }
    for (int i = t; i < 768; i += 512){
        int row = i >> 4, ch = i & 15;
        int nb = ld_idx(Eidx, bid * KN + row, i64);
        stage8(A + row * SA + 128 + ch * 8, dout, ((long)b * LL + nb) * HH + ch * 8, f32);
    }
    if (t < HH) hv0f[t] = ldf(dout, (long)bid * HH + t, f32);
    if (t < KN){ rowsum[t] = 0.f; rowsq[t] = 0.f; }

    bf16x8 B2[4];
    {
        const u16* bp = ws + OFF_W12T + (long)(w * 16 + r16) * 128 + q8;
#pragma unroll
        for (int k = 0; k < 4; k++) B2[k] = *(const bf16x8*)(bp + k * 32);
    }
    __syncthreads();

    calc_beff(hv0f, ws + OFF_W11T, b11, beff, f32, lane, w);

    f32x4 acc[3];
    zero_acc3(acc);
    mfma_regB<8, SA>(A, B1, acc, lane);
    store_m8(acc, M1, beff[w * 16 + r16], lane, w, true);

    bf16x8 B3[4];
    {
        const u16* bp = ws + OFF_W13T + (long)(w * 16 + r16) * 128 + q8;
#pragma unroll
        for (int k = 0; k < 4; k++) B3[k] = *(const bf16x8*)(bp + k * 32);
    }
    __syncthreads();

    zero_acc3(acc);
    mfma_regB<4, SM>(M1, B2, acc, lane);
    store_m8(acc, M2, ldf(b12, w * 16 + r16, f32), lane, w, true);
    __syncthreads();

    zero_acc3(acc);
    mfma_regB<4, SM>(M2, B3, acc, lane);

    const int q = lane >> 4;
    const int c0 = w * 16 + r16;
    float vals[3][4];
    {
        float bc = ldf(b13, c0, f32);
#pragma unroll
        for (int mt = 0; mt < 3; mt++)
#pragma unroll
            for (int i = 0; i < 4; i++){
                int r = mt * 16 + q * 4 + i;
                /* residual h_E re-read from global (L2-hit) since A was overwritten */
                vals[mt][i] = acc[mt][i] + bc + ldf(hE, ((long)bid * KN + r) * HH + c0, f32);
            }
    }
#pragma unroll
    for (int mt = 0; mt < 3; mt++)
#pragma unroll
        for (int i = 0; i < 4; i++){
            float s = vals[mt][i], sq2 = vals[mt][i] * vals[mt][i];
            s += __shfl_xor(s, 1); sq2 += __shfl_xor(sq2, 1);
            s += __shfl_xor(s, 2); sq2 += __shfl_xor(sq2, 2);
            s += __shfl_xor(s, 4); sq2 += __shfl_xor(sq2, 4);
            s += __shfl_xor(s, 8); sq2 += __shfl_xor(sq2, 8);
            if (r16 == 0){
                int r = mt * 16 + q * 4 + i;
                atomicAdd(&rowsum[r], s);
                atomicAdd(&rowsq[r], sq2);
            }
        }
    __syncthreads();
    if (t < KN){
        float mu = rowsum[t] * (1.0f / 128.0f);
        float var = rowsq[t] * (1.0f / 128.0f) - mu * mu;
        rowsum[t] = mu;
        rowsq[t] = rsqrtf(var + 1e-5f);
    }
    __syncthreads();

    {
        long ebase = (long)BB * LL * HH;
        float g = ldf(ln3s, c0, f32), be = ldf(ln3b, c0, f32);
#pragma unroll
        for (int mt = 0; mt < 3; mt++)
#pragma unroll
            for (int i = 0; i < 4; i++){
                int r = mt * 16 + q * 4 + i;
                long base = ebase + ((long)bid * KN + r) * HH;
                st_out(dout, base + c0, (vals[mt][i] - rowsum[r]) * rowsq[r] + be, f32);
            }
    }
}

extern "C" void kernel_launch(void* const* d_in, const int* in_sizes, int n_in,
                              void* d_out, int out_size, void* d_ws, size_t ws_size,
                              hipStream_t stream) {
    const void* hV    = d_in[0];
    const void* hE    = d_in[1];
    const void* Eidx  = d_in[2];
    const void* maskV = d_in[3];
    const void* maskA = d_in[4];
    const void* W1  = d_in[5];  const void* b1  = d_in[6];
    const void* W2  = d_in[7];  const void* b2  = d_in[8];
    const void* W3  = d_in[9];  const void* b3  = d_in[10];
    const void* W11 = d_in[11]; const void* b11 = d_in[12];
    const void* W12 = d_in[13]; const void* b12 = d_in[14];
    const void* W13 = d_in[15]; const void* b13 = d_in[16];
    const void* Wi  = d_in[17]; const void* bi  = d_in[18];
    const void* Wo  = d_in[19]; const void* bo  = d_in[20];
    const void* ln1s = d_in[21]; const void* ln1b = d_in[22];
    const void* ln2s = d_in[23]; const void* ln2b = d_in[24];
    const void* ln3s = d_in[25]; const void* ln3b = d_in[26];

    u16* ws = (u16*)d_ws;

    detect_kernel<<<1, 64, 0, stream>>>(ln1s, maskV, Eidx, (int*)d_ws);
    prep_kernel<<<(PREP_N + 255) / 256, 256, 0, stream>>>(W1, W2, W3, W11, W12, W13, Wi, Wo, ws);
    node_kernel<<<NBLK, 512, 0, stream>>>(hV, hE, Eidx, maskA,
                                          b1, b2, b3, ln1s, ln1b, ws);
    ffn_kernel<<<NBLK / 16, 512, 0, stream>>>(maskV, bi, bo, ln2s, ln2b, ws, d_out);
    edge_kernel<<<NBLK, 512, 0, stream>>>(hE, Eidx, b11, b12, b13,
                                          ln3s, ln3b, ws, d_out);
}